// Round 10
// baseline (449.308 us; speedup 1.0000x reference)
//
#include <hip/hip_runtime.h>

// DropBlock on (B,C,H,W)=(64,256,56,56), block_size=7, drop_prob=0.1
// mask_u is (B,C,50,50); gamma = 0.1/49 * 56^2/50^2.

#define BB 64
#define CC 256
#define HH 56
#define WW 56
#define HMM 50
#define WMM 50
#define BS 7

static constexpr unsigned int NPLANE = BB * CC;            // 16384
static constexpr unsigned int NTOT   = BB * CC * HH * WW;  // 51380224
static constexpr unsigned int NV     = NTOT / 4;           // 12845056 float4s
static constexpr unsigned int PLANEF = HMM * WMM;          // 2500 floats/plane
static constexpr unsigned int PLANE4 = PLANEF / 4;         // 625 float4/plane
static constexpr unsigned int MGRID  = NPLANE / 2;         // 8192 mask blocks
static constexpr unsigned int AGRID  = 2048;               // apply blocks (G11 cap)
static constexpr unsigned int ASTRIDE = AGRID * 256;       // 524288

typedef float f32x4 __attribute__((ext_vector_type(4)));

// 2 planes per 256-thread block (R9 structure, neutral-vs-R4 and full
// occupancy). Stage 20 KB coalesced -> barrier -> waves 0/1 each ballot one
// plane out of LDS; h-dilation by shifts, v-dilation by 3 shfl_up rounds.
// Change vs R9: write ONE count per block (waves 0/1 combine via LDS) so the
// apply kernel can cheaply reduce 8192 counts itself — the separate scale
// kernel (+launch, ~10us) is eliminated. All waves reach both barriers.
__global__ void __launch_bounds__(256) dropblock_mask_kernel(
    const float* __restrict__ mask_u,
    unsigned long long* __restrict__ rowmask,
    unsigned int* __restrict__ block_cnt,
    float gamma)
{
    const unsigned int tid  = threadIdx.x;
    const unsigned int wid  = tid >> 6;
    const unsigned int lane = tid & 63u;

    __shared__ float4 lds4[2 * PLANE4];  // 20 KB: 2 planes of raw mask_u
    __shared__ unsigned int csh[2];
    const float* lds = reinterpret_cast<const float*>(lds4);

    // Phase 1: block-cooperative staging, 16 B/lane coalesced stream.
    {
        const float4* src = reinterpret_cast<const float4*>(mask_u)
                          + (size_t)blockIdx.x * (2 * PLANE4);
        #pragma unroll
        for (unsigned int r = 0; r < 5; ++r) {
            unsigned int idx = tid + r * 256u;
            if (idx < 2 * PLANE4) lds4[idx] = src[idx];
        }
    }
    __syncthreads();

    if (wid < 2) {
        const unsigned int plane = blockIdx.x * 2u + wid;

        // Phase 2: ballot out of LDS (lanes 0..49 read consecutive words of
        // row i: <=2 lanes/bank aliasing, conflict-free).
        const float* mu = lds + wid * PLANEF;
        unsigned long long my_d = 0ull;  // lane i: horizontally-dilated row i

        #pragma unroll
        for (int i = 0; i < HMM; ++i) {
            float v = (lane < WMM) ? mu[i * WMM + lane] : 1.0f;  // 1.0>=gamma -> 0
            unsigned long long m = __ballot(v < gamma);
            unsigned long long d = m | (m << 1);  // shifts {0,1}
            d |= d << 2;                          // {0..3}
            d |= d << 3;                          // {0..6}
            if (lane == (unsigned)i) my_d = d;
        }

        // vertical dilation: OR rows [i-6, i]; lanes >= 50 start at 0 so rows
        // 50..55 get only the valid tail window; shfl_up with lane<delta
        // returns own value (idempotent under OR)
        unsigned long long blocked = my_d;
        blocked |= __shfl_up(blocked, 1, 64);
        blocked |= __shfl_up(blocked, 2, 64);
        blocked |= __shfl_up(blocked, 3, 64);

        if (lane < HH) rowmask[plane * HH + lane] = blocked;

        unsigned int cnt = __popcll(blocked);  // lanes >= 56: blocked==0
        #pragma unroll
        for (int off = 32; off > 0; off >>= 1)
            cnt += __shfl_down(cnt, off, 64);
        if (lane == 0) csh[wid] = cnt;
    }
    __syncthreads();
    if (tid == 0) block_cnt[blockIdx.x] = csh[0] + csh[1];
}

// Grid-stride apply, 2048 blocks (G11: cap grid, stride the rest — replaces
// 50176 tiny blocks whose dispatch ramp alone is ~20us). Prologue: every
// block redundantly reduces the 8192 block counts (32 KB, L2-resident,
// 8 uint4/thread) and computes scale locally — no separate scale kernel, no
// dependency stall. Loop body is byte-equivalent to the proven flat apply:
// every load/store is a contiguous 1 KB wave segment.
__global__ void __launch_bounds__(256) dropblock_apply_kernel(
    const float* __restrict__ x,
    const unsigned long long* __restrict__ rowmask,
    const unsigned int* __restrict__ block_cnt,
    float* __restrict__ out)
{
    const unsigned int tid  = threadIdx.x;
    const unsigned int wid  = tid >> 6;
    const unsigned int lane = tid & 63u;

    __shared__ unsigned int ssum[4];
    __shared__ float scale_sh;

    // reduce 8192 counts = 2048 uint4; 8 per thread
    {
        const uint4* c4 = reinterpret_cast<const uint4*>(block_cnt);
        unsigned int s = 0;
        #pragma unroll
        for (unsigned int k = 0; k < 8; ++k) {
            uint4 v = c4[tid + k * 256u];
            s += v.x + v.y + v.z + v.w;
        }
        #pragma unroll
        for (int off = 32; off > 0; off >>= 1)
            s += __shfl_down(s, off, 64);
        if (lane == 0) ssum[wid] = s;
        __syncthreads();
        if (tid == 0) {
            unsigned int tot = ssum[0] + ssum[1] + ssum[2] + ssum[3];
            // NTOT exactly representable in fp32; kept-count rounding error
            // <= 2 ulp -> scale rel err ~1e-7, way under threshold.
            scale_sh = (float)NTOT / (float)(NTOT - tot);
        }
        __syncthreads();
    }
    const float scale = scale_sh;

    for (unsigned int idx = blockIdx.x * 256u + tid; idx < NV; idx += ASTRIDE) {
        // idx -> (plane, row, col) ; 784 float4s per plane, 14 per row
        unsigned int plane = idx / (HH * WW / 4);            // / 784
        unsigned int rem   = idx - plane * (HH * WW / 4);
        unsigned int row   = rem / (WW / 4);                 // / 14
        unsigned int colv  = rem - row * (WW / 4);
        unsigned int col   = colv * 4;

        unsigned long long rm = rowmask[plane * HH + row];
        float4 xv = reinterpret_cast<const float4*>(x)[idx];
        float4 o;
        o.x = ((rm >> (col + 0)) & 1ull) ? 0.0f : xv.x * scale;
        o.y = ((rm >> (col + 1)) & 1ull) ? 0.0f : xv.y * scale;
        o.z = ((rm >> (col + 2)) & 1ull) ? 0.0f : xv.z * scale;
        o.w = ((rm >> (col + 3)) & 1ull) ? 0.0f : xv.w * scale;
        reinterpret_cast<float4*>(out)[idx] = o;
    }
}

extern "C" void kernel_launch(void* const* d_in, const int* in_sizes, int n_in,
                              void* d_out, int out_size, void* d_ws, size_t ws_size,
                              hipStream_t stream) {
    const float* x      = (const float*)d_in[0];
    const float* mask_u = (const float*)d_in[1];
    float* out          = (float*)d_out;

    // ws layout (everything fully overwritten each call -> re-poison safe):
    //   [0, 32768)        : per-block drop counts (8192 u32)
    //   [32768, +7340032) : 16384 planes * 56 rows * uint64 row bitmasks
    unsigned int* block_cnt     = (unsigned int*)d_ws;
    unsigned long long* rowmask = (unsigned long long*)((char*)d_ws + 32768);

    // gamma computed in double then cast to fp32, matching JAX's weak-typed
    // promotion of the Python float in (mask_u < gamma).
    const double gd = 0.1 / ((double)BS * BS) * ((double)HH * HH) /
                      (((double)HH - BS + 1.0) * ((double)HH - BS + 1.0));
    const float gamma = (float)gd;

    dropblock_mask_kernel<<<MGRID, 256, 0, stream>>>(
        mask_u, rowmask, block_cnt, gamma);

    dropblock_apply_kernel<<<AGRID, 256, 0, stream>>>(
        x, rowmask, block_cnt, out);
}

// Round 11
// 436.512 us; speedup vs baseline: 1.0293x; 1.0293x over previous
//
#include <hip/hip_runtime.h>

// DropBlock on (B,C,H,W)=(64,256,56,56), block_size=7, drop_prob=0.1
// mask_u is (B,C,50,50); gamma = 0.1/49 * 56^2/50^2.

#define BB 64
#define CC 256
#define HH 56
#define WW 56
#define HMM 50
#define WMM 50
#define BS 7

static constexpr unsigned int NPLANE = BB * CC;            // 16384
static constexpr unsigned int NTOT   = BB * CC * HH * WW;  // 51380224
static constexpr unsigned int NV     = NTOT / 4;           // 12845056 float4s
static constexpr unsigned int PLANEF = HMM * WMM;          // 2500 floats/plane
static constexpr unsigned int PLANE4 = PLANEF / 4;         // 625 float4/plane

typedef float f32x4 __attribute__((ext_vector_type(4)));

// 2 planes per 256-thread block (R9 config: full occupancy, measured tie with
// R4's 4-plane). Stage 20 KB coalesced -> barrier -> waves 0/1 each ballot one
// plane from LDS; h-dilation by shifts, v-dilation by 3 shfl_up rounds.
__global__ void __launch_bounds__(256) dropblock_mask_kernel(
    const float* __restrict__ mask_u,
    unsigned long long* __restrict__ rowmask,
    unsigned int* __restrict__ plane_cnt,
    float gamma)
{
    const unsigned int tid   = threadIdx.x;
    const unsigned int wid   = tid >> 6;
    const unsigned int lane  = tid & 63u;

    __shared__ float4 lds4[2 * PLANE4];  // 20 KB: 2 planes of raw mask_u
    const float* lds = reinterpret_cast<const float*>(lds4);

    // Phase 1: block-cooperative staging, 16 B/lane coalesced stream.
    {
        const float4* src = reinterpret_cast<const float4*>(mask_u)
                          + (size_t)blockIdx.x * (2 * PLANE4);
        #pragma unroll
        for (unsigned int r = 0; r < 5; ++r) {
            unsigned int idx = tid + r * 256u;
            if (idx < 2 * PLANE4) lds4[idx] = src[idx];
        }
    }
    __syncthreads();

    if (wid >= 2) return;  // staging-only waves (exit after barrier)

    const unsigned int plane = blockIdx.x * 2u + wid;

    // Phase 2: per-wave ballot out of LDS (lanes 0..49 read consecutive words
    // of row i: <=2 lanes/bank aliasing, conflict-free).
    const float* mu = lds + wid * PLANEF;
    unsigned long long my_d = 0ull;  // lane i holds horizontally-dilated row i

    #pragma unroll
    for (int i = 0; i < HMM; ++i) {
        float v = (lane < WMM) ? mu[i * WMM + lane] : 1.0f;  // 1.0 >= gamma -> bit 0
        unsigned long long m = __ballot(v < gamma);
        // horizontal dilation: OR of shifts 0..6
        unsigned long long d = m | (m << 1);  // {0,1}
        d |= d << 2;                          // {0..3}
        d |= d << 3;                          // {0..6}
        if (lane == (unsigned)i) my_d = d;
    }

    // vertical dilation: lane i needs OR of rows [i-6, i] (lanes >= 50 hold 0,
    // so rows 50..55 correctly get only the tail window; shfl_up for lane<delta
    // returns own value, which is idempotent under OR)
    unsigned long long blocked = my_d;
    blocked |= __shfl_up(blocked, 1, 64);  // window {0,1}
    blocked |= __shfl_up(blocked, 2, 64);  // window {0..3}
    blocked |= __shfl_up(blocked, 3, 64);  // window {0..6}

    if (lane < HH) rowmask[plane * HH + lane] = blocked;

    // dropped-pixel count for this plane (lanes >= 56 have blocked==0)
    unsigned int cnt = __popcll(blocked);
    #pragma unroll
    for (int off = 32; off > 0; off >>= 1)
        cnt += __shfl_down(cnt, off, 64);
    if (lane == 0) plane_cnt[plane] = cnt;
}

// Single-block reduction of the 16384 per-plane counts -> scale factor.
// (R4 form — measured best.)
__global__ void __launch_bounds__(1024) dropblock_scale_kernel(
    const unsigned int* __restrict__ plane_cnt,
    float* __restrict__ scale_out)
{
    __shared__ unsigned int ssum[16];
    const unsigned int t = threadIdx.x;

    const uint4* pc4 = reinterpret_cast<const uint4*>(plane_cnt);  // 4096 uint4
    uint4 a = pc4[t];
    uint4 b = pc4[t + 1024];
    uint4 c = pc4[t + 2048];
    uint4 d = pc4[t + 3072];
    unsigned int s = a.x + a.y + a.z + a.w
                   + b.x + b.y + b.z + b.w
                   + c.x + c.y + c.z + c.w
                   + d.x + d.y + d.z + d.w;

    #pragma unroll
    for (int off = 32; off > 0; off >>= 1)
        s += __shfl_down(s, off, 64);
    if ((t & 63u) == 0u) ssum[t >> 6] = s;
    __syncthreads();

    if (t < 16) {
        unsigned int v = ssum[t];
        #pragma unroll
        for (int off = 8; off > 0; off >>= 1)
            v += __shfl_down(v, off, 64);
        if (t == 0) {
            // NTOT exactly representable in fp32; kept-count rounding error
            // <= 2 ulp -> scale rel err ~1e-7, way under threshold.
            *scale_out = (float)NTOT / (float)(NTOT - v);
        }
    }
}

// Flat apply (R4's proven structure: 50176 tiny blocks, 1 float4/thread,
// contiguous 1KB wave segments). ONE isolated change vs R4: NONTEMPORAL
// STORE. out is write-once-never-read; normal stores allocate 205.5 MB of
// lines in L2/L3 per iteration, evicting the x/rowmask/mask_u streams.
// nt store = no-allocate. (R2 tested nt only bundled with nt-loads +
// pairing; nt-store-alone was never isolated.) Loads stay plain.
__global__ void __launch_bounds__(256) dropblock_apply_kernel(
    const float* __restrict__ x,
    const unsigned long long* __restrict__ rowmask,
    const float* __restrict__ scale_ptr,
    float* __restrict__ out)
{
    unsigned int idx = blockIdx.x * 256u + threadIdx.x;
    if (idx >= NV) return;

    const float scale = *scale_ptr;  // uniform scalar load, precomputed

    // idx -> (plane, row, col) ; 784 float4s per plane, 14 per row
    unsigned int plane = idx / (HH * WW / 4);            // / 784
    unsigned int rem   = idx - plane * (HH * WW / 4);
    unsigned int row   = rem / (WW / 4);                 // / 14
    unsigned int colv  = rem - row * (WW / 4);
    unsigned int col   = colv * 4;

    unsigned long long rm = rowmask[plane * HH + row];
    f32x4 xv = reinterpret_cast<const f32x4*>(x)[idx];
    f32x4 o;
    o[0] = ((rm >> (col + 0)) & 1ull) ? 0.0f : xv[0] * scale;
    o[1] = ((rm >> (col + 1)) & 1ull) ? 0.0f : xv[1] * scale;
    o[2] = ((rm >> (col + 2)) & 1ull) ? 0.0f : xv[2] * scale;
    o[3] = ((rm >> (col + 3)) & 1ull) ? 0.0f : xv[3] * scale;
    __builtin_nontemporal_store(o, reinterpret_cast<f32x4*>(out) + idx);
}

extern "C" void kernel_launch(void* const* d_in, const int* in_sizes, int n_in,
                              void* d_out, int out_size, void* d_ws, size_t ws_size,
                              hipStream_t stream) {
    const float* x      = (const float*)d_in[0];
    const float* mask_u = (const float*)d_in[1];
    float* out          = (float*)d_out;

    // ws layout (everything fully overwritten each call -> re-poison safe):
    //   [0, 64)           : scale (float, own cache line)
    //   [64, 64+65536)    : per-plane drop counts (16384 u32)
    //   [65600, +7340032) : 16384 planes * 56 rows * uint64 row bitmasks
    float* scale_ws             = (float*)d_ws;
    unsigned int* plane_cnt     = (unsigned int*)((char*)d_ws + 64);
    unsigned long long* rowmask = (unsigned long long*)((char*)d_ws + 65600);

    // gamma computed in double then cast to fp32, matching JAX's weak-typed
    // promotion of the Python float in (mask_u < gamma).
    const double gd = 0.1 / ((double)BS * BS) * ((double)HH * HH) /
                      (((double)HH - BS + 1.0) * ((double)HH - BS + 1.0));
    const float gamma = (float)gd;

    dropblock_mask_kernel<<<NPLANE / 2, 256, 0, stream>>>(
        mask_u, rowmask, plane_cnt, gamma);

    dropblock_scale_kernel<<<1, 1024, 0, stream>>>(plane_cnt, scale_ws);

    dropblock_apply_kernel<<<(NV + 255u) / 256u, 256, 0, stream>>>(
        x, rowmask, scale_ws, out);
}